// Round 1
// baseline (4542.887 us; speedup 1.0000x reference)
//
#include <hip/hip_runtime.h>

// ---------------------------------------------------------------------------
// BiLSTM seq2seq + attention + vocab softmax for MI355X (gfx950).
// B=4, T=128, E=512, H=512, D=1024, V=32000.
// Strategy: bf16 MFMA (16x16x32) everywhere, fp32 accumulate/gates.
//  - Global "fragment-swizzled" layouts [K/8][M][8] bf16 -> LDS-free GEMM.
//  - Persistent LSTM kernels, Wh fragments pinned in registers, ping-pong h,
//    device-scope atomic spin barriers between the co-resident workgroups.
// ---------------------------------------------------------------------------

typedef __attribute__((ext_vector_type(8))) short bf16x8;   // 8 bf16 = 4 VGPRs
typedef __attribute__((ext_vector_type(4))) float f32x4;

__device__ __forceinline__ short f2bf(float f) {  // RNE fp32 -> bf16
  unsigned u = __builtin_bit_cast(unsigned, f);
  u += 0x7fffu + ((u >> 16) & 1u);
  return (short)(u >> 16);
}
__device__ __forceinline__ float b2f(short s) {
  unsigned u = ((unsigned)(unsigned short)s) << 16;
  return __builtin_bit_cast(float, u);
}
__device__ __forceinline__ float sigf(float x) { return 1.f / (1.f + __expf(-x)); }
__device__ __forceinline__ float tanhf_fast(float x) {
  x = fminf(fmaxf(x, -15.f), 15.f);
  float e = __expf(2.f * x);
  return (e - 1.f) / (e + 1.f);
}

// ---- workspace layout (all offsets 256B-aligned) --------------------------
#define OFF_CNT   ((size_t)0)                       // 3 u32 barrier counters
#define OFF_HBF   ((size_t)256)                     // enc fwd h  [2][16][512] bf16
#define OFF_HBB   (OFF_HBF + 2*16*512*2)            // enc bwd h
#define OFF_HBD   (OFF_HBB + 2*16*512*2)            // dec h      [2][16][1024] bf16
#define ZERO_SZ   (OFF_HBD + 2*16*1024*2)           // everything above is memset(0)
#define OFF_ENCX  (ZERO_SZ)                         // enc_x swz [64][512][8] bf16
#define OFF_DECX  (OFF_ENCX + (size_t)64*512*8*2)
#define OFF_WXF   (OFF_DECX + (size_t)64*512*8*2)   // Wx_f swz [64][2048][8]
#define OFF_WXB   (OFF_WXF + (size_t)512*2048*2)
#define OFF_WXD   (OFF_WXB + (size_t)512*2048*2)    // Wx_d swz [64][4096][8]
#define OFF_WOS   (OFF_WXD + (size_t)512*4096*2)    // Wo  swz [128][32000][8]
#define OFF_XWF   (OFF_WOS + (size_t)1024*32000*2)  // xw_f fp32 [512][2048]
#define OFF_XWB   (OFF_XWF + (size_t)512*2048*4)
#define OFF_XWD   (OFF_XWB + (size_t)512*2048*4)    // xw_d fp32 [512][4096]
#define OFF_ENCO  (OFF_XWD + (size_t)512*4096*4)    // enc_out fp32 [4][128][1024]
#define OFF_ENCT  (OFF_ENCO + (size_t)4*128*1024*4) // enc_out^T fp32 [4][1024][128]
#define OFF_DECO  (OFF_ENCT + (size_t)4*128*1024*4) // dec_out fp32 [4][128][1024]
#define OFF_ATTN  (OFF_DECO + (size_t)4*128*1024*4) // attn swz [128][512][8] bf16
#define OFF_LOG   (OFF_ATTN + (size_t)128*512*8*2)  // logits bf16 [512][32000]
#define WS_NEED   (OFF_LOG + (size_t)512*32000*2)

// ---- inter-workgroup barrier (monotonic counter, agent scope) -------------
__device__ __forceinline__ void wg_barrier(unsigned* cnt, unsigned target) {
  __threadfence();          // flush my stores to the device coherence point
  __syncthreads();
  if (threadIdx.x == 0) {
    __hip_atomic_fetch_add(cnt, 1u, __ATOMIC_RELEASE, __HIP_MEMORY_SCOPE_AGENT);
    int guard = 0;
    while (__hip_atomic_load(cnt, __ATOMIC_ACQUIRE, __HIP_MEMORY_SCOPE_AGENT) < target) {
      __builtin_amdgcn_s_sleep(1);
      if (++guard > (1 << 21)) break;   // hang safety valve (fails visibly instead)
    }
  }
  __syncthreads();
  __threadfence();          // invalidate caches before re-reading h
}

// ---- embedding gather -> fragment-swizzled bf16 A matrix ------------------
// dst[e8][m][j] = bf16(emb[seq[m]][e8*8+j]);  grid(16,8) x 256
__global__ __launch_bounds__(256) void gather_embed(const int* __restrict__ seq,
                                                    const float* __restrict__ emb,
                                                    short* __restrict__ dst) {
  int m  = blockIdx.y * 64 + (threadIdx.x & 63);
  int e8 = blockIdx.x * 4 + (threadIdx.x >> 6);
  int id = seq[m];
  const float* src = emb + (size_t)id * 512 + e8 * 8;
  bf16x8 v;
#pragma unroll
  for (int j = 0; j < 8; ++j) v[j] = f2bf(src[j]);
  *(bf16x8*)(dst + ((size_t)e8 * 512 + m) * 8) = v;
}

// ---- fp32 [K][N] weight -> fragment-swizzled bf16 [K/8][N][8] -------------
// grid(N/256, K/8) x 256
__global__ __launch_bounds__(256) void swizzle_B(const float* __restrict__ W,
                                                 short* __restrict__ dst, int N) {
  int k8 = blockIdx.y;
  int n  = blockIdx.x * 256 + threadIdx.x;
  const float* src = W + (size_t)k8 * 8 * N + n;
  bf16x8 v;
#pragma unroll
  for (int j = 0; j < 8; ++j) v[j] = f2bf(src[(size_t)j * N]);
  *(bf16x8*)(dst + ((size_t)k8 * N + n) * 8) = v;
}

// ---- LDS-free bf16 MFMA GEMM on swizzled operands -------------------------
// C[M][N] = A[M][K] @ B[K][N]; 128x128 block, 4 waves, 64x64 per wave.
// grid(N/128, M/128) x 256
template <int BF16OUT>
__global__ __launch_bounds__(256) void gemm_swz(const short* __restrict__ A,
                                                const short* __restrict__ B,
                                                float* __restrict__ Cf,
                                                short* __restrict__ Cb,
                                                int M, int N, int K) {
  const int wv = threadIdx.x >> 6, lane = threadIdx.x & 63;
  const int q = lane >> 4, l15 = lane & 15;
  const int m0 = blockIdx.y * 128 + (wv >> 1) * 64;
  const int n0 = blockIdx.x * 128 + (wv & 1) * 64;
  f32x4 acc[4][4];
#pragma unroll
  for (int i = 0; i < 4; ++i)
#pragma unroll
    for (int j = 0; j < 4; ++j) acc[i][j] = (f32x4){0.f, 0.f, 0.f, 0.f};
  const int KS = K >> 5;
  for (int ks = 0; ks < KS; ++ks) {
    const size_t k8 = (size_t)(ks * 4 + q);
    const short* Ap = A + (k8 * M + m0 + l15) * 8;
    const short* Bp = B + (k8 * N + n0 + l15) * 8;
    bf16x8 av[4], bv[4];
#pragma unroll
    for (int i = 0; i < 4; ++i) av[i] = *(const bf16x8*)(Ap + i * 128);
#pragma unroll
    for (int j = 0; j < 4; ++j) bv[j] = *(const bf16x8*)(Bp + j * 128);
#pragma unroll
    for (int i = 0; i < 4; ++i)
#pragma unroll
      for (int j = 0; j < 4; ++j)
        acc[i][j] = __builtin_amdgcn_mfma_f32_16x16x32_bf16(av[i], bv[j], acc[i][j], 0, 0, 0);
  }
#pragma unroll
  for (int i = 0; i < 4; ++i)
#pragma unroll
    for (int j = 0; j < 4; ++j)
#pragma unroll
      for (int r = 0; r < 4; ++r) {
        size_t idx = (size_t)(m0 + i * 16 + q * 4 + r) * N + (n0 + j * 16 + l15);
        if (BF16OUT) Cb[idx] = f2bf(acc[i][j][r]);
        else         Cf[idx] = acc[i][j][r];
      }
}

// ---- encoder LSTM: both directions, persistent, 64 WGs x 256 --------------
// WG wid: dir=wid>>5, owns 16 hidden units u0=(wid&31)*16. Wave w = gate w.
__global__ __launch_bounds__(256, 1) void lstm_enc(
    const float* __restrict__ Wh_f, const float* __restrict__ Wh_b,
    const float* __restrict__ xw_f, const float* __restrict__ xw_b,
    const float* __restrict__ b_f, const float* __restrict__ b_b,
    short* hb_f, short* hb_b, float* enc_out, float* encT, unsigned* cnt) {
  const int wid = blockIdx.x;
  const int dir = wid >> 5;
  const int u0  = (wid & 31) * 16;
  const int tid = threadIdx.x;
  const int w = tid >> 6, lane = tid & 63;
  const int q = lane >> 4, l15 = lane & 15;
  const float* Wh   = dir ? Wh_b : Wh_f;
  const float* xw   = dir ? xw_b : xw_f;
  const float* bias = dir ? b_b : b_f;
  short* hb = dir ? hb_b : hb_f;
  unsigned* mycnt = cnt + dir;

  __shared__ float zb[4][4][16];  // [gate][b][unit]
  __shared__ float cb[4][16];     // cell state [b][unit]
  if (tid < 64) cb[tid >> 4][tid & 15] = 0.f;

  const int col = w * 512 + u0 + l15;       // gate column in [0,2048)
  const float bcol = bias[col];
  bf16x8 wfrag[16];                          // Wh fragments, live in VGPRs
#pragma unroll
  for (int ks = 0; ks < 16; ++ks) {
    bf16x8 v;
#pragma unroll
    for (int jj = 0; jj < 8; ++jj) {
      int k = ks * 32 + q * 8 + jj;
      v[jj] = f2bf(Wh[(size_t)k * 2048 + col]);
    }
    wfrag[ks] = v;
  }
  __syncthreads();

#pragma unroll 1
  for (int t = 0; t < 128; ++t) {
    const short* hp = hb + (t & 1) * 8192 + l15 * 512 + q * 8;
    f32x4 acc = (f32x4){0.f, 0.f, 0.f, 0.f};
#pragma unroll
    for (int ks = 0; ks < 16; ++ks) {
      bf16x8 af = *(const bf16x8*)(hp + ks * 32);
      acc = __builtin_amdgcn_mfma_f32_16x16x32_bf16(af, wfrag[ks], acc, 0, 0, 0);
    }
    const int tx = dir ? (127 - t) : t;      // bwd consumes reversed time
    if (q == 0) {                            // lanes 0..15 hold rows(b)=reg
#pragma unroll
      for (int r = 0; r < 4; ++r)
        zb[w][r][l15] = acc[r] + xw[((size_t)(r * 128 + tx)) * 2048 + col] + bcol;
    }
    __syncthreads();
    if (tid < 64) {
      int b = tid >> 4, u = tid & 15;
      float zi = zb[0][b][u], zf = zb[1][b][u], zg = zb[2][b][u], zo = zb[3][b][u];
      float c = sigf(zf) * cb[b][u] + sigf(zi) * tanhf_fast(zg);
      cb[b][u] = c;
      float h = sigf(zo) * tanhf_fast(c);
      hb[((t & 1) ^ 1) * 8192 + b * 512 + u0 + u] = f2bf(h);
      int d = dir * 512 + u0 + u;
      enc_out[((size_t)(b * 128 + tx)) * 1024 + d] = h;
      encT[((size_t)(b * 1024 + d)) * 128 + tx] = h;
    }
    if (t < 127) wg_barrier(mycnt, (unsigned)(t + 1) * 32u);
  }
}

// ---- decoder LSTM: 64 WGs x 256, D=1024 -----------------------------------
__global__ __launch_bounds__(256, 1) void lstm_dec(
    const float* __restrict__ Wh_d, const float* __restrict__ xw_d,
    const float* __restrict__ b_d, const float* __restrict__ enc_out,
    short* hb, float* dec_out, unsigned* cnt) {
  const int u0  = blockIdx.x * 16;
  const int tid = threadIdx.x;
  const int w = tid >> 6, lane = tid & 63;
  const int q = lane >> 4, l15 = lane & 15;

  __shared__ float zb[4][4][16];
  __shared__ float cb[4][16];

  const int col = w * 1024 + u0 + l15;      // gate column in [0,4096)
  const float bcol = b_d[col];
  bf16x8 wfrag[32];
#pragma unroll
  for (int ks = 0; ks < 32; ++ks) {
    bf16x8 v;
#pragma unroll
    for (int jj = 0; jj < 8; ++jj) {
      int k = ks * 32 + q * 8 + jj;
      v[jj] = f2bf(Wh_d[(size_t)k * 4096 + col]);
    }
    wfrag[ks] = v;
  }
  // h0 = enc_out[:, 127, :], c0 = 0
  if (tid < 64) {
    int b = tid >> 4, u = tid & 15;
    cb[b][u] = 0.f;
    float h0 = enc_out[((size_t)(b * 128 + 127)) * 1024 + u0 + u];
    hb[b * 1024 + u0 + u] = f2bf(h0);       // parity-0 buffer
  }
  wg_barrier(cnt, 64u);

#pragma unroll 1
  for (int t = 0; t < 128; ++t) {
    const short* hp = hb + (t & 1) * 16384 + l15 * 1024 + q * 8;
    f32x4 acc = (f32x4){0.f, 0.f, 0.f, 0.f};
#pragma unroll
    for (int ks = 0; ks < 32; ++ks) {
      bf16x8 af = *(const bf16x8*)(hp + ks * 32);
      acc = __builtin_amdgcn_mfma_f32_16x16x32_bf16(af, wfrag[ks], acc, 0, 0, 0);
    }
    if (q == 0) {
#pragma unroll
      for (int r = 0; r < 4; ++r)
        zb[w][r][l15] = acc[r] + xw_d[((size_t)(r * 128 + t)) * 4096 + col] + bcol;
    }
    __syncthreads();
    if (tid < 64) {
      int b = tid >> 4, u = tid & 15;
      float zi = zb[0][b][u], zf = zb[1][b][u], zg = zb[2][b][u], zo = zb[3][b][u];
      float c = sigf(zf) * cb[b][u] + sigf(zi) * tanhf_fast(zg);
      cb[b][u] = c;
      float h = sigf(zo) * tanhf_fast(c);
      hb[((t & 1) ^ 1) * 16384 + b * 1024 + u0 + u] = f2bf(h);
      dec_out[((size_t)(b * 128 + t)) * 1024 + u0 + u] = h;
    }
    if (t < 127) wg_barrier(cnt, (unsigned)(t + 2) * 64u);
  }
}

// ---- attention: one block per (b,t); writes swizzled bf16 attn ------------
__global__ __launch_bounds__(256) void attention(
    const float* __restrict__ dec_out, const float* __restrict__ enc_out,
    const float* __restrict__ encT, const float* __restrict__ scale,
    short* __restrict__ attn_swz) {
  const int m = blockIdx.x, b = m >> 7, tid = threadIdx.x;
  __shared__ float dec_s[1024], scl_s[1024];
  __shared__ float red[256], wts[128], sred[2];
  for (int d = tid; d < 1024; d += 256) {
    dec_s[d] = dec_out[(size_t)m * 1024 + d];
    scl_s[d] = scale[d];
  }
  __syncthreads();
  const int s = tid & 127, half = tid >> 7;
  float sc = 0.f;
  const float* ep = encT + (size_t)b * 1024 * 128 + s;
  for (int d = half * 512; d < half * 512 + 512; ++d)
    sc += tanhf_fast(dec_s[d] + ep[(size_t)d * 128]) * scl_s[d];
  red[tid] = sc;
  __syncthreads();
  float v = 0.f;
  if (tid < 128) { v = red[tid] + red[tid + 128]; wts[tid] = v; }
  __syncthreads();
  if (tid < 64) {
    float mx = fmaxf(wts[tid], wts[tid + 64]);
    for (int off = 32; off; off >>= 1) mx = fmaxf(mx, __shfl_down(mx, off));
    if (tid == 0) sred[0] = mx;
  }
  __syncthreads();
  const float MX = sred[0];
  if (tid < 128) { v = __expf(v - MX); wts[tid] = v; }
  __syncthreads();
  if (tid < 64) {
    float sm = wts[tid] + wts[tid + 64];
    for (int off = 32; off; off >>= 1) sm += __shfl_down(sm, off);
    if (tid == 0) sred[1] = sm;
  }
  __syncthreads();
  const float inv = 1.f / sred[1];
  if (tid < 128) wts[tid] = v * inv;
  __syncthreads();
#pragma unroll
  for (int kk = 0; kk < 4; ++kk) {
    int d = tid + kk * 256;
    float a = 0.f;
    for (int ss = 0; ss < 128; ++ss)
      a += wts[ss] * enc_out[((size_t)(b * 128 + ss)) * 1024 + d];
    attn_swz[((size_t)(d >> 3) * 512 + m) * 8 + (d & 7)] = f2bf(a);
  }
}

// ---- row softmax over 32000 vocab, bf16 logits + bias -> fp32 probs -------
__global__ __launch_bounds__(256) void softmax_out(const short* __restrict__ logits,
                                                   const float* __restrict__ bo,
                                                   float* __restrict__ out) {
  const int m = blockIdx.x, tid = threadIdx.x;
  __shared__ float red[256];
  const short* lp = logits + (size_t)m * 32000;
  float mx = -1e30f;
  for (int n = tid; n < 32000; n += 256) mx = fmaxf(mx, b2f(lp[n]) + bo[n]);
  red[tid] = mx;
  __syncthreads();
  for (int s2 = 128; s2 > 0; s2 >>= 1) {
    if (tid < s2) red[tid] = fmaxf(red[tid], red[tid + s2]);
    __syncthreads();
  }
  const float M = red[0];
  __syncthreads();
  float sm = 0.f;
  for (int n = tid; n < 32000; n += 256) sm += __expf(b2f(lp[n]) + bo[n] - M);
  red[tid] = sm;
  __syncthreads();
  for (int s2 = 128; s2 > 0; s2 >>= 1) {
    if (tid < s2) red[tid] += red[tid + s2];
    __syncthreads();
  }
  const float inv = 1.f / red[0];
  for (int n = tid; n < 32000; n += 256)
    out[(size_t)m * 32000 + n] = __expf(b2f(lp[n]) + bo[n] - M) * inv;
}

// ---------------------------------------------------------------------------
extern "C" void kernel_launch(void* const* d_in, const int* in_sizes, int n_in,
                              void* d_out, int out_size, void* d_ws, size_t ws_size,
                              hipStream_t stream) {
  (void)in_sizes; (void)n_in; (void)out_size;
  if (ws_size < WS_NEED) return;  // fails validation visibly rather than OOB

  const int*   input_seq  = (const int*)d_in[0];
  const int*   output_seq = (const int*)d_in[1];
  const float* enc_emb    = (const float*)d_in[2];
  const float* dec_emb    = (const float*)d_in[3];
  const float* Wx_f = (const float*)d_in[4];
  const float* Wh_f = (const float*)d_in[5];
  const float* b_f  = (const float*)d_in[6];
  const float* Wx_b = (const float*)d_in[7];
  const float* Wh_b = (const float*)d_in[8];
  const float* b_b  = (const float*)d_in[9];
  const float* Wx_d = (const float*)d_in[10];
  const float* Wh_d = (const float*)d_in[11];
  const float* b_d  = (const float*)d_in[12];
  const float* attn_scale = (const float*)d_in[13];
  const float* Wo   = (const float*)d_in[14];
  const float* bo   = (const float*)d_in[15];
  float* out = (float*)d_out;

  char* ws = (char*)d_ws;
  unsigned* cnt   = (unsigned*)(ws + OFF_CNT);
  short* hbf      = (short*)(ws + OFF_HBF);
  short* hbb      = (short*)(ws + OFF_HBB);
  short* hbd      = (short*)(ws + OFF_HBD);
  short* encx     = (short*)(ws + OFF_ENCX);
  short* decx     = (short*)(ws + OFF_DECX);
  short* wxf_s    = (short*)(ws + OFF_WXF);
  short* wxb_s    = (short*)(ws + OFF_WXB);
  short* wxd_s    = (short*)(ws + OFF_WXD);
  short* wo_s     = (short*)(ws + OFF_WOS);
  float* xw_f     = (float*)(ws + OFF_XWF);
  float* xw_b     = (float*)(ws + OFF_XWB);
  float* xw_d     = (float*)(ws + OFF_XWD);
  float* enc_out  = (float*)(ws + OFF_ENCO);
  float* encT     = (float*)(ws + OFF_ENCT);
  float* dec_out  = (float*)(ws + OFF_DECO);
  short* attn_s   = (short*)(ws + OFF_ATTN);
  short* logits   = (short*)(ws + OFF_LOG);

  // zero barrier counters + h ping-pong buffers (incl. padding rows 4..15)
  hipMemsetAsync(ws, 0, ZERO_SZ, stream);

  // embeddings -> swizzled bf16 A matrices
  gather_embed<<<dim3(16, 8), 256, 0, stream>>>(input_seq, enc_emb, encx);
  gather_embed<<<dim3(16, 8), 256, 0, stream>>>(output_seq, dec_emb, decx);

  // weights -> swizzled bf16 B matrices
  swizzle_B<<<dim3(8, 64), 256, 0, stream>>>(Wx_f, wxf_s, 2048);
  swizzle_B<<<dim3(8, 64), 256, 0, stream>>>(Wx_b, wxb_s, 2048);
  swizzle_B<<<dim3(16, 64), 256, 0, stream>>>(Wx_d, wxd_s, 4096);
  swizzle_B<<<dim3(125, 128), 256, 0, stream>>>(Wo, wo_s, 32000);

  // input projections (bias added inside LSTM kernels)
  gemm_swz<0><<<dim3(16, 4), 256, 0, stream>>>(encx, wxf_s, xw_f, nullptr, 512, 2048, 512);
  gemm_swz<0><<<dim3(16, 4), 256, 0, stream>>>(encx, wxb_s, xw_b, nullptr, 512, 2048, 512);
  gemm_swz<0><<<dim3(32, 4), 256, 0, stream>>>(decx, wxd_s, xw_d, nullptr, 512, 4096, 512);

  // recurrences
  lstm_enc<<<64, 256, 0, stream>>>(Wh_f, Wh_b, xw_f, xw_b, b_f, b_b,
                                   hbf, hbb, enc_out, encT, cnt);
  lstm_dec<<<64, 256, 0, stream>>>(Wh_d, xw_d, b_d, enc_out, hbd, dec_out, cnt + 2);

  // attention -> swizzled bf16 attn matrix
  attention<<<512, 256, 0, stream>>>(dec_out, enc_out, encT, attn_scale, attn_s);

  // logits = attn @ Wo (bf16 out), then row softmax with bias
  gemm_swz<1><<<dim3(250, 4), 256, 0, stream>>>(attn_s, wo_s, nullptr, logits, 512, 32000, 1024);
  softmax_out<<<512, 256, 0, stream>>>(logits, bo, out);
}

// Round 2
// 2156.380 us; speedup vs baseline: 2.1067x; 2.1067x over previous
//
#include <hip/hip_runtime.h>

// ---------------------------------------------------------------------------
// BiLSTM seq2seq + attention + vocab softmax for MI355X (gfx950).
// B=4, T=128, E=512, H=512, D=1024, V=32000.
// Round 2: persistent LSTMs now sync via TAGGED ATOMIC WORDS (relaxed,
// agent scope -> single sc0/sc1 dword access to MALL) instead of fences +
// spin barriers. Round-1 fences compiled to full L2 wb/inv per step
// (FETCH_SIZE 29 GB on lstm_dec); this removes all cache maintenance.
// h word = (tag<<16)|bf16(h); tag for h_t is t+1; ping-pong on t&1.
// ---------------------------------------------------------------------------

typedef __attribute__((ext_vector_type(8))) short bf16x8;   // 8 bf16 = 4 VGPRs
typedef __attribute__((ext_vector_type(4))) float f32x4;

__device__ __forceinline__ short f2bf(float f) {  // RNE fp32 -> bf16
  unsigned u = __builtin_bit_cast(unsigned, f);
  u += 0x7fffu + ((u >> 16) & 1u);
  return (short)(u >> 16);
}
__device__ __forceinline__ float b2f(short s) {
  unsigned u = ((unsigned)(unsigned short)s) << 16;
  return __builtin_bit_cast(float, u);
}
__device__ __forceinline__ float sigf(float x) { return 1.f / (1.f + __expf(-x)); }
__device__ __forceinline__ float tanhf_fast(float x) {
  x = fminf(fmaxf(x, -15.f), 15.f);
  float e = __expf(2.f * x);
  return (e - 1.f) / (e + 1.f);
}

// relaxed agent-scope atomics: single coherent dword access, no cache flush
__device__ __forceinline__ unsigned ld_coh(const unsigned* p) {
  return __hip_atomic_load(p, __ATOMIC_RELAXED, __HIP_MEMORY_SCOPE_AGENT);
}
__device__ __forceinline__ void st_coh(unsigned* p, unsigned v) {
  __hip_atomic_store(p, v, __ATOMIC_RELAXED, __HIP_MEMORY_SCOPE_AGENT);
}

// ---- workspace layout -----------------------------------------------------
#define OFF_HBF   ((size_t)0)                       // enc fwd h [2][4*512] u32 tagged
#define OFF_HBB   (OFF_HBF + 2*2048*4)              // enc bwd h
#define OFF_HBD   (OFF_HBB + 2*2048*4)              // dec h [2][4*1024] u32 tagged
#define OFF_ENCX  (OFF_HBD + 2*4096*4)              // enc_x swz [64][512][8] bf16
#define OFF_DECX  (OFF_ENCX + (size_t)64*512*8*2)
#define OFF_WXF   (OFF_DECX + (size_t)64*512*8*2)   // Wx_f swz [64][2048][8]
#define OFF_WXB   (OFF_WXF + (size_t)512*2048*2)
#define OFF_WXD   (OFF_WXB + (size_t)512*2048*2)    // Wx_d swz [64][4096][8]
#define OFF_WOS   (OFF_WXD + (size_t)512*4096*2)    // Wo  swz [128][32000][8]
#define OFF_XWF   (OFF_WOS + (size_t)1024*32000*2)  // xw_f fp32 [512][2048]
#define OFF_XWB   (OFF_XWF + (size_t)512*2048*4)
#define OFF_XWD   (OFF_XWB + (size_t)512*2048*4)    // xw_d fp32 [512][4096]
#define OFF_ENCO  (OFF_XWD + (size_t)512*4096*4)    // enc_out fp32 [4][128][1024]
#define OFF_ENCT  (OFF_ENCO + (size_t)4*128*1024*4) // enc_out^T fp32 [4][1024][128]
#define OFF_DECO  (OFF_ENCT + (size_t)4*128*1024*4) // dec_out fp32 [4][128][1024]
#define OFF_ATTN  (OFF_DECO + (size_t)4*128*1024*4) // attn swz [128][512][8] bf16
#define OFF_LOG   (OFF_ATTN + (size_t)128*512*8*2)  // logits bf16 [512][32000]
#define WS_NEED   (OFF_LOG + (size_t)512*32000*2)

// ---- embedding gather -> fragment-swizzled bf16 A matrix ------------------
__global__ __launch_bounds__(256) void gather_embed(const int* __restrict__ seq,
                                                    const float* __restrict__ emb,
                                                    short* __restrict__ dst) {
  int m  = blockIdx.y * 64 + (threadIdx.x & 63);
  int e8 = blockIdx.x * 4 + (threadIdx.x >> 6);
  int id = seq[m];
  const float* src = emb + (size_t)id * 512 + e8 * 8;
  bf16x8 v;
#pragma unroll
  for (int j = 0; j < 8; ++j) v[j] = f2bf(src[j]);
  *(bf16x8*)(dst + ((size_t)e8 * 512 + m) * 8) = v;
}

// ---- fp32 [K][N] weight -> fragment-swizzled bf16 [K/8][N][8] -------------
__global__ __launch_bounds__(256) void swizzle_B(const float* __restrict__ W,
                                                 short* __restrict__ dst, int N) {
  int k8 = blockIdx.y;
  int n  = blockIdx.x * 256 + threadIdx.x;
  const float* src = W + (size_t)k8 * 8 * N + n;
  bf16x8 v;
#pragma unroll
  for (int j = 0; j < 8; ++j) v[j] = f2bf(src[(size_t)j * N]);
  *(bf16x8*)(dst + ((size_t)k8 * N + n) * 8) = v;
}

// ---- LDS-free bf16 MFMA GEMM on swizzled operands -------------------------
template <int BF16OUT>
__global__ __launch_bounds__(256) void gemm_swz(const short* __restrict__ A,
                                                const short* __restrict__ B,
                                                float* __restrict__ Cf,
                                                short* __restrict__ Cb,
                                                int M, int N, int K) {
  const int wv = threadIdx.x >> 6, lane = threadIdx.x & 63;
  const int q = lane >> 4, l15 = lane & 15;
  const int m0 = blockIdx.y * 128 + (wv >> 1) * 64;
  const int n0 = blockIdx.x * 128 + (wv & 1) * 64;
  f32x4 acc[4][4];
#pragma unroll
  for (int i = 0; i < 4; ++i)
#pragma unroll
    for (int j = 0; j < 4; ++j) acc[i][j] = (f32x4){0.f, 0.f, 0.f, 0.f};
  const int KS = K >> 5;
  for (int ks = 0; ks < KS; ++ks) {
    const size_t k8 = (size_t)(ks * 4 + q);
    const short* Ap = A + (k8 * M + m0 + l15) * 8;
    const short* Bp = B + (k8 * N + n0 + l15) * 8;
    bf16x8 av[4], bv[4];
#pragma unroll
    for (int i = 0; i < 4; ++i) av[i] = *(const bf16x8*)(Ap + i * 128);
#pragma unroll
    for (int j = 0; j < 4; ++j) bv[j] = *(const bf16x8*)(Bp + j * 128);
#pragma unroll
    for (int i = 0; i < 4; ++i)
#pragma unroll
      for (int j = 0; j < 4; ++j)
        acc[i][j] = __builtin_amdgcn_mfma_f32_16x16x32_bf16(av[i], bv[j], acc[i][j], 0, 0, 0);
  }
#pragma unroll
  for (int i = 0; i < 4; ++i)
#pragma unroll
    for (int j = 0; j < 4; ++j)
#pragma unroll
      for (int r = 0; r < 4; ++r) {
        size_t idx = (size_t)(m0 + i * 16 + q * 4 + r) * N + (n0 + j * 16 + l15);
        if (BF16OUT) Cb[idx] = f2bf(acc[i][j][r]);
        else         Cf[idx] = acc[i][j][r];
      }
}

// ---- encoder LSTM: fwd+bwd, 64 WGs x 256, tagged-atomic handoff -----------
__global__ __launch_bounds__(256, 1) void lstm_enc(
    const float* __restrict__ Wh_f, const float* __restrict__ Wh_b,
    const float* __restrict__ xw_f, const float* __restrict__ xw_b,
    const float* __restrict__ b_f, const float* __restrict__ b_b,
    unsigned* hb_f, unsigned* hb_b, float* enc_out, float* encT) {
  const int wid = blockIdx.x;
  const int dir = wid >> 5;
  const int u0  = (wid & 31) * 16;
  const int tid = threadIdx.x;
  const int w = tid >> 6, lane = tid & 63;
  const int q = lane >> 4, l15 = lane & 15;
  const float* Wh   = dir ? Wh_b : Wh_f;
  const float* xw   = dir ? xw_b : xw_f;
  const float* bias = dir ? b_b : b_f;
  unsigned* hb = dir ? hb_b : hb_f;

  __shared__ short hs[5][520];    // h staged bf16; row 4 = zeros (pad rows)
  __shared__ float zb[4][4][16];  // [gate][b][unit]
  __shared__ float cb[4][16];     // cell state [b][unit]
  if (tid < 64) cb[tid >> 4][tid & 15] = 0.f;
  for (int k = tid; k < 520; k += 256) hs[4][k] = 0;

  const int col = w * 512 + u0 + l15;       // gate column in [0,2048)
  const float bcol = bias[col];
  bf16x8 wfrag[16];                          // Wh fragments, live in VGPRs
#pragma unroll
  for (int ks = 0; ks < 16; ++ks) {
    bf16x8 v;
#pragma unroll
    for (int jj = 0; jj < 8; ++jj) {
      int k = ks * 32 + q * 8 + jj;
      v[jj] = f2bf(Wh[(size_t)k * 2048 + col]);
    }
    wfrag[ks] = v;
  }
  // publish h0 = 0 with tag 1 into parity-0 buffer (own slice only)
  if (tid < 64) {
    int b = tid >> 4, u = tid & 15;
    st_coh(hb + b * 512 + u0 + u, 1u << 16);
  }
  const short* hp = hs[(l15 < 4) ? l15 : 4];

#pragma unroll 1
  for (int t = 0; t < 128; ++t) {
    // spin-read h_t (tag t+1) from parity t&1; stage into LDS
    const unsigned exp = (unsigned)(t + 1);
    const unsigned* src = hb + (t & 1) * 2048;
    unsigned v[8];
#pragma unroll
    for (int j = 0; j < 8; ++j) v[j] = ld_coh(src + j * 256 + tid);
#pragma unroll
    for (int j = 0; j < 8; ++j) {
      int g = 0;
      while ((v[j] >> 16) != exp) {
        __builtin_amdgcn_s_sleep(2);
        v[j] = ld_coh(src + j * 256 + tid);
        if (++g > (1 << 17)) break;   // visible failure instead of hang
      }
      unsigned idx = j * 256 + tid;
      hs[idx >> 9][idx & 511] = (short)(v[j] & 0xffffu);
    }
    __syncthreads();

    f32x4 a0 = (f32x4){0.f, 0.f, 0.f, 0.f}, a1 = a0;
#pragma unroll
    for (int ks = 0; ks < 16; ks += 2) {
      bf16x8 f0 = *(const bf16x8*)(hp + ks * 32 + q * 8);
      bf16x8 f1 = *(const bf16x8*)(hp + (ks + 1) * 32 + q * 8);
      a0 = __builtin_amdgcn_mfma_f32_16x16x32_bf16(f0, wfrag[ks], a0, 0, 0, 0);
      a1 = __builtin_amdgcn_mfma_f32_16x16x32_bf16(f1, wfrag[ks + 1], a1, 0, 0, 0);
    }
    const int tx = dir ? (127 - t) : t;      // bwd consumes reversed time
    if (q == 0) {                            // C rows 0..3 = batch
#pragma unroll
      for (int r = 0; r < 4; ++r)
        zb[w][r][l15] = a0[r] + a1[r] + xw[((size_t)(r * 128 + tx)) * 2048 + col] + bcol;
    }
    __syncthreads();
    if (tid < 64) {
      int b = tid >> 4, u = tid & 15;
      float zi = zb[0][b][u], zf = zb[1][b][u], zg = zb[2][b][u], zo = zb[3][b][u];
      float c = sigf(zf) * cb[b][u] + sigf(zi) * tanhf_fast(zg);
      cb[b][u] = c;
      float h = sigf(zo) * tanhf_fast(c);
      if (t < 127)
        st_coh(hb + ((t + 1) & 1) * 2048 + b * 512 + u0 + u,
               ((unsigned)(t + 2) << 16) | (unsigned short)f2bf(h));
      int d = dir * 512 + u0 + u;
      enc_out[((size_t)(b * 128 + tx)) * 1024 + d] = h;
      encT[((size_t)(b * 1024 + d)) * 128 + tx] = h;
    }
    __syncthreads();   // protect hs before next step's overwrite
  }
}

// ---- decoder LSTM: 64 WGs x 256, D=1024, tagged-atomic handoff ------------
__global__ __launch_bounds__(256, 1) void lstm_dec(
    const float* __restrict__ Wh_d, const float* __restrict__ xw_d,
    const float* __restrict__ b_d, const float* __restrict__ enc_out,
    unsigned* hb, float* dec_out) {
  const int u0  = blockIdx.x * 16;
  const int tid = threadIdx.x;
  const int w = tid >> 6, lane = tid & 63;
  const int q = lane >> 4, l15 = lane & 15;

  __shared__ short hs[5][1032];   // row 4 = zeros
  __shared__ float zb[4][4][16];
  __shared__ float cb[4][16];
  if (tid < 64) cb[tid >> 4][tid & 15] = 0.f;
  for (int k = tid; k < 1032; k += 256) hs[4][k] = 0;

  const int col = w * 1024 + u0 + l15;      // gate column in [0,4096)
  const float bcol = b_d[col];
  bf16x8 wfrag[32];
#pragma unroll
  for (int ks = 0; ks < 32; ++ks) {
    bf16x8 v;
#pragma unroll
    for (int jj = 0; jj < 8; ++jj) {
      int k = ks * 32 + q * 8 + jj;
      v[jj] = f2bf(Wh_d[(size_t)k * 4096 + col]);
    }
    wfrag[ks] = v;
  }
  // publish h0 = enc_out[:,127,:] with tag 1, parity 0 (own slice)
  if (tid < 64) {
    int b = tid >> 4, u = tid & 15;
    float h0 = enc_out[((size_t)(b * 128 + 127)) * 1024 + u0 + u];
    st_coh(hb + b * 1024 + u0 + u, (1u << 16) | (unsigned short)f2bf(h0));
  }
  const short* hp = hs[(l15 < 4) ? l15 : 4];

#pragma unroll 1
  for (int t = 0; t < 128; ++t) {
    const unsigned exp = (unsigned)(t + 1);
    const unsigned* src = hb + (t & 1) * 4096;
    unsigned v[16];
#pragma unroll
    for (int j = 0; j < 16; ++j) v[j] = ld_coh(src + j * 256 + tid);
#pragma unroll
    for (int j = 0; j < 16; ++j) {
      int g = 0;
      while ((v[j] >> 16) != exp) {
        __builtin_amdgcn_s_sleep(2);
        v[j] = ld_coh(src + j * 256 + tid);
        if (++g > (1 << 17)) break;
      }
      unsigned idx = j * 256 + tid;
      hs[idx >> 10][idx & 1023] = (short)(v[j] & 0xffffu);
    }
    __syncthreads();

    f32x4 a0 = (f32x4){0.f, 0.f, 0.f, 0.f}, a1 = a0;
#pragma unroll
    for (int ks = 0; ks < 32; ks += 2) {
      bf16x8 f0 = *(const bf16x8*)(hp + ks * 32 + q * 8);
      bf16x8 f1 = *(const bf16x8*)(hp + (ks + 1) * 32 + q * 8);
      a0 = __builtin_amdgcn_mfma_f32_16x16x32_bf16(f0, wfrag[ks], a0, 0, 0, 0);
      a1 = __builtin_amdgcn_mfma_f32_16x16x32_bf16(f1, wfrag[ks + 1], a1, 0, 0, 0);
    }
    if (q == 0) {
#pragma unroll
      for (int r = 0; r < 4; ++r)
        zb[w][r][l15] = a0[r] + a1[r] + xw_d[((size_t)(r * 128 + t)) * 4096 + col] + bcol;
    }
    __syncthreads();
    if (tid < 64) {
      int b = tid >> 4, u = tid & 15;
      float zi = zb[0][b][u], zf = zb[1][b][u], zg = zb[2][b][u], zo = zb[3][b][u];
      float c = sigf(zf) * cb[b][u] + sigf(zi) * tanhf_fast(zg);
      cb[b][u] = c;
      float h = sigf(zo) * tanhf_fast(c);
      if (t < 127)
        st_coh(hb + ((t + 1) & 1) * 4096 + b * 1024 + u0 + u,
               ((unsigned)(t + 2) << 16) | (unsigned short)f2bf(h));
      dec_out[((size_t)(b * 128 + t)) * 1024 + u0 + u] = h;
    }
    __syncthreads();
  }
}

// ---- attention: one block per (b,t); writes swizzled bf16 attn ------------
__global__ __launch_bounds__(256) void attention(
    const float* __restrict__ dec_out, const float* __restrict__ enc_out,
    const float* __restrict__ encT, const float* __restrict__ scale,
    short* __restrict__ attn_swz) {
  const int m = blockIdx.x, b = m >> 7, tid = threadIdx.x;
  __shared__ float dec_s[1024], scl_s[1024];
  __shared__ float red[256], wts[128], sred[2];
  for (int d = tid; d < 1024; d += 256) {
    dec_s[d] = dec_out[(size_t)m * 1024 + d];
    scl_s[d] = scale[d];
  }
  __syncthreads();
  const int s = tid & 127, half = tid >> 7;
  float sc = 0.f;
  const float* ep = encT + (size_t)b * 1024 * 128 + s;
  for (int d = half * 512; d < half * 512 + 512; ++d)
    sc += tanhf_fast(dec_s[d] + ep[(size_t)d * 128]) * scl_s[d];
  red[tid] = sc;
  __syncthreads();
  float v = 0.f;
  if (tid < 128) { v = red[tid] + red[tid + 128]; wts[tid] = v; }
  __syncthreads();
  if (tid < 64) {
    float mx = fmaxf(wts[tid], wts[tid + 64]);
    for (int off = 32; off; off >>= 1) mx = fmaxf(mx, __shfl_down(mx, off));
    if (tid == 0) sred[0] = mx;
  }
  __syncthreads();
  const float MX = sred[0];
  if (tid < 128) { v = __expf(v - MX); wts[tid] = v; }
  __syncthreads();
  if (tid < 64) {
    float sm = wts[tid] + wts[tid + 64];
    for (int off = 32; off; off >>= 1) sm += __shfl_down(sm, off);
    if (tid == 0) sred[1] = sm;
  }
  __syncthreads();
  const float inv = 1.f / sred[1];
  if (tid < 128) wts[tid] = v * inv;
  __syncthreads();
#pragma unroll
  for (int kk = 0; kk < 4; ++kk) {
    int d = tid + kk * 256;
    float a = 0.f;
    for (int ss = 0; ss < 128; ++ss)
      a += wts[ss] * enc_out[((size_t)(b * 128 + ss)) * 1024 + d];
    attn_swz[((size_t)(d >> 3) * 512 + m) * 8 + (d & 7)] = f2bf(a);
  }
}

// ---- row softmax over 32000 vocab, bf16 logits + bias -> fp32 probs -------
__global__ __launch_bounds__(256) void softmax_out(const short* __restrict__ logits,
                                                   const float* __restrict__ bo,
                                                   float* __restrict__ out) {
  const int m = blockIdx.x, tid = threadIdx.x;
  __shared__ float red[256];
  const short* lp = logits + (size_t)m * 32000;
  float mx = -1e30f;
  for (int n = tid; n < 32000; n += 256) mx = fmaxf(mx, b2f(lp[n]) + bo[n]);
  red[tid] = mx;
  __syncthreads();
  for (int s2 = 128; s2 > 0; s2 >>= 1) {
    if (tid < s2) red[tid] = fmaxf(red[tid], red[tid + s2]);
    __syncthreads();
  }
  const float M = red[0];
  __syncthreads();
  float sm = 0.f;
  for (int n = tid; n < 32000; n += 256) sm += __expf(b2f(lp[n]) + bo[n] - M);
  red[tid] = sm;
  __syncthreads();
  for (int s2 = 128; s2 > 0; s2 >>= 1) {
    if (tid < s2) red[tid] += red[tid + s2];
    __syncthreads();
  }
  const float inv = 1.f / red[0];
  for (int n = tid; n < 32000; n += 256)
    out[(size_t)m * 32000 + n] = __expf(b2f(lp[n]) + bo[n] - M) * inv;
}

// ---------------------------------------------------------------------------
extern "C" void kernel_launch(void* const* d_in, const int* in_sizes, int n_in,
                              void* d_out, int out_size, void* d_ws, size_t ws_size,
                              hipStream_t stream) {
  (void)in_sizes; (void)n_in; (void)out_size;
  if (ws_size < WS_NEED) return;

  const int*   input_seq  = (const int*)d_in[0];
  const int*   output_seq = (const int*)d_in[1];
  const float* enc_emb    = (const float*)d_in[2];
  const float* dec_emb    = (const float*)d_in[3];
  const float* Wx_f = (const float*)d_in[4];
  const float* Wh_f = (const float*)d_in[5];
  const float* b_f  = (const float*)d_in[6];
  const float* Wx_b = (const float*)d_in[7];
  const float* Wh_b = (const float*)d_in[8];
  const float* b_b  = (const float*)d_in[9];
  const float* Wx_d = (const float*)d_in[10];
  const float* Wh_d = (const float*)d_in[11];
  const float* b_d  = (const float*)d_in[12];
  const float* attn_scale = (const float*)d_in[13];
  const float* Wo   = (const float*)d_in[14];
  const float* bo   = (const float*)d_in[15];
  float* out = (float*)d_out;

  char* ws = (char*)d_ws;
  unsigned* hbf   = (unsigned*)(ws + OFF_HBF);
  unsigned* hbb   = (unsigned*)(ws + OFF_HBB);
  unsigned* hbd   = (unsigned*)(ws + OFF_HBD);
  short* encx     = (short*)(ws + OFF_ENCX);
  short* decx     = (short*)(ws + OFF_DECX);
  short* wxf_s    = (short*)(ws + OFF_WXF);
  short* wxb_s    = (short*)(ws + OFF_WXB);
  short* wxd_s    = (short*)(ws + OFF_WXD);
  short* wo_s     = (short*)(ws + OFF_WOS);
  float* xw_f     = (float*)(ws + OFF_XWF);
  float* xw_b     = (float*)(ws + OFF_XWB);
  float* xw_d     = (float*)(ws + OFF_XWD);
  float* enc_out  = (float*)(ws + OFF_ENCO);
  float* encT     = (float*)(ws + OFF_ENCT);
  float* dec_out  = (float*)(ws + OFF_DECO);
  short* attn_s   = (short*)(ws + OFF_ATTN);
  short* logits   = (short*)(ws + OFF_LOG);

  // NOTE: no memset needed — 0xAA poison gives tag 0xAAAA, never a valid tag.

  gather_embed<<<dim3(16, 8), 256, 0, stream>>>(input_seq, enc_emb, encx);
  gather_embed<<<dim3(16, 8), 256, 0, stream>>>(output_seq, dec_emb, decx);

  swizzle_B<<<dim3(8, 64), 256, 0, stream>>>(Wx_f, wxf_s, 2048);
  swizzle_B<<<dim3(8, 64), 256, 0, stream>>>(Wx_b, wxb_s, 2048);
  swizzle_B<<<dim3(16, 64), 256, 0, stream>>>(Wx_d, wxd_s, 4096);
  swizzle_B<<<dim3(125, 128), 256, 0, stream>>>(Wo, wo_s, 32000);

  gemm_swz<0><<<dim3(16, 4), 256, 0, stream>>>(encx, wxf_s, xw_f, nullptr, 512, 2048, 512);
  gemm_swz<0><<<dim3(16, 4), 256, 0, stream>>>(encx, wxb_s, xw_b, nullptr, 512, 2048, 512);
  gemm_swz<0><<<dim3(32, 4), 256, 0, stream>>>(decx, wxd_s, xw_d, nullptr, 512, 4096, 512);

  lstm_enc<<<64, 256, 0, stream>>>(Wh_f, Wh_b, xw_f, xw_b, b_f, b_b,
                                   hbf, hbb, enc_out, encT);
  lstm_dec<<<64, 256, 0, stream>>>(Wh_d, xw_d, b_d, enc_out, hbd, dec_out);

  attention<<<512, 256, 0, stream>>>(dec_out, enc_out, encT, attn_scale, attn_s);

  gemm_swz<1><<<dim3(250, 4), 256, 0, stream>>>(attn_s, wo_s, nullptr, logits, 512, 32000, 1024);
  softmax_out<<<512, 256, 0, stream>>>(logits, bo, out);
}

// Round 3
// 1174.544 us; speedup vs baseline: 3.8678x; 1.8359x over previous
//
#include <hip/hip_runtime.h>

// ---------------------------------------------------------------------------
// BiLSTM seq2seq + attention + vocab softmax for MI355X (gfx950).
// B=4, T=128, E=512, H=512, D=1024, V=32000.
// Round 3:
//  - LSTM spin-wait now re-polls ALL h words in parallel each round (round-2
//    version spun per-word sequentially -> ~15 serial MALL round trips/step).
//  - xw prefetched one step ahead (off the critical path); 2 barriers/step.
//  - Wo swizzle + xw_d GEMM folded into the enc-LSTM launch as extra blocks
//    (LSTM blocks 0..63 dispatch first; swizzle work fills the idle CUs).
// ---------------------------------------------------------------------------

typedef __attribute__((ext_vector_type(8))) short bf16x8;   // 8 bf16 = 4 VGPRs
typedef __attribute__((ext_vector_type(4))) float f32x4;

__device__ __forceinline__ short f2bf(float f) {  // RNE fp32 -> bf16
  unsigned u = __builtin_bit_cast(unsigned, f);
  u += 0x7fffu + ((u >> 16) & 1u);
  return (short)(u >> 16);
}
__device__ __forceinline__ float b2f(short s) {
  unsigned u = ((unsigned)(unsigned short)s) << 16;
  return __builtin_bit_cast(float, u);
}
__device__ __forceinline__ float sigf(float x) { return 1.f / (1.f + __expf(-x)); }
__device__ __forceinline__ float tanhf_fast(float x) {
  x = fminf(fmaxf(x, -15.f), 15.f);
  float e = __expf(2.f * x);
  return (e - 1.f) / (e + 1.f);
}

// relaxed agent-scope atomics: single coherent dword access, no cache flush
__device__ __forceinline__ unsigned ld_coh(const unsigned* p) {
  return __hip_atomic_load(p, __ATOMIC_RELAXED, __HIP_MEMORY_SCOPE_AGENT);
}
__device__ __forceinline__ void st_coh(unsigned* p, unsigned v) {
  __hip_atomic_store(p, v, __ATOMIC_RELAXED, __HIP_MEMORY_SCOPE_AGENT);
}

// ---- workspace layout -----------------------------------------------------
#define OFF_HBF   ((size_t)0)                       // enc fwd h [2][4*512] u32 tagged
#define OFF_HBB   (OFF_HBF + 2*2048*4)              // enc bwd h
#define OFF_HBD   (OFF_HBB + 2*2048*4)              // dec h [2][4*1024] u32 tagged
#define OFF_ENCX  (OFF_HBD + 2*4096*4)              // enc_x swz [64][512][8] bf16
#define OFF_DECX  (OFF_ENCX + (size_t)64*512*8*2)
#define OFF_WXF   (OFF_DECX + (size_t)64*512*8*2)   // Wx_f swz [64][2048][8]
#define OFF_WXB   (OFF_WXF + (size_t)512*2048*2)
#define OFF_WXD   (OFF_WXB + (size_t)512*2048*2)    // Wx_d swz [64][4096][8]
#define OFF_WOS   (OFF_WXD + (size_t)512*4096*2)    // Wo  swz [128][32000][8]
#define OFF_XWF   (OFF_WOS + (size_t)1024*32000*2)  // xw_f fp32 [512][2048]
#define OFF_XWB   (OFF_XWF + (size_t)512*2048*4)
#define OFF_XWD   (OFF_XWB + (size_t)512*2048*4)    // xw_d fp32 [512][4096]
#define OFF_ENCO  (OFF_XWD + (size_t)512*4096*4)    // enc_out fp32 [4][128][1024]
#define OFF_ENCT  (OFF_ENCO + (size_t)4*128*1024*4) // enc_out^T fp32 [4][1024][128]
#define OFF_DECO  (OFF_ENCT + (size_t)4*128*1024*4) // dec_out fp32 [4][128][1024]
#define OFF_ATTN  (OFF_DECO + (size_t)4*128*1024*4) // attn swz [128][512][8] bf16
#define OFF_LOG   (OFF_ATTN + (size_t)128*512*8*2)  // logits bf16 [512][32000]
#define WS_NEED   (OFF_LOG + (size_t)512*32000*2)

// ---- shared bodies --------------------------------------------------------
__device__ __forceinline__ void gather_body(const int* seq, const float* emb,
                                            short* dst, int bx, int by) {
  int m  = by * 64 + (threadIdx.x & 63);
  int e8 = bx * 4 + (threadIdx.x >> 6);
  int id = seq[m];
  const float* src = emb + (size_t)id * 512 + e8 * 8;
  bf16x8 v;
#pragma unroll
  for (int j = 0; j < 8; ++j) v[j] = f2bf(src[j]);
  *(bf16x8*)(dst + ((size_t)e8 * 512 + m) * 8) = v;
}

__device__ __forceinline__ void swz_body(const float* W, short* dst, int N,
                                         int k8, int n) {
  const float* src = W + (size_t)k8 * 8 * N + n;
  bf16x8 v;
#pragma unroll
  for (int j = 0; j < 8; ++j) v[j] = f2bf(src[(size_t)j * N]);
  *(bf16x8*)(dst + ((size_t)k8 * N + n) * 8) = v;
}

// LDS-free bf16 MFMA GEMM on [K/8][M][8]-swizzled operands; 128x128/block.
__device__ __forceinline__ void gemm_body(const short* __restrict__ A,
                                          const short* __restrict__ B,
                                          float* Cf, short* Cb,
                                          int M, int N, int K,
                                          int bx, int by, bool bf16out) {
  const int wv = threadIdx.x >> 6, lane = threadIdx.x & 63;
  const int q = lane >> 4, l15 = lane & 15;
  const int m0 = by * 128 + (wv >> 1) * 64;
  const int n0 = bx * 128 + (wv & 1) * 64;
  f32x4 acc[4][4];
#pragma unroll
  for (int i = 0; i < 4; ++i)
#pragma unroll
    for (int j = 0; j < 4; ++j) acc[i][j] = (f32x4){0.f, 0.f, 0.f, 0.f};
  const int KS = K >> 5;
  for (int ks = 0; ks < KS; ++ks) {
    const size_t k8 = (size_t)(ks * 4 + q);
    const short* Ap = A + (k8 * M + m0 + l15) * 8;
    const short* Bp = B + (k8 * N + n0 + l15) * 8;
    bf16x8 av[4], bv[4];
#pragma unroll
    for (int i = 0; i < 4; ++i) av[i] = *(const bf16x8*)(Ap + i * 128);
#pragma unroll
    for (int j = 0; j < 4; ++j) bv[j] = *(const bf16x8*)(Bp + j * 128);
#pragma unroll
    for (int i = 0; i < 4; ++i)
#pragma unroll
      for (int j = 0; j < 4; ++j)
        acc[i][j] = __builtin_amdgcn_mfma_f32_16x16x32_bf16(av[i], bv[j], acc[i][j], 0, 0, 0);
  }
#pragma unroll
  for (int i = 0; i < 4; ++i)
#pragma unroll
    for (int j = 0; j < 4; ++j)
#pragma unroll
      for (int r = 0; r < 4; ++r) {
        size_t idx = (size_t)(m0 + i * 16 + q * 4 + r) * N + (n0 + j * 16 + l15);
        if (bf16out) Cb[idx] = f2bf(acc[i][j][r]);
        else         Cf[idx] = acc[i][j][r];
      }
}

// ---- prep: both gathers + three Wx swizzles, role-dispatched --------------
__global__ __launch_bounds__(256) void prep(
    const int* __restrict__ iseq, const int* __restrict__ oseq,
    const float* __restrict__ enc_emb, const float* __restrict__ dec_emb,
    const float* __restrict__ Wx_f, const float* __restrict__ Wx_b,
    const float* __restrict__ Wx_d,
    short* encx, short* decx, short* wxf_s, short* wxb_s, short* wxd_s) {
  int bid = blockIdx.x;
  if (bid < 128)        { gather_body(iseq, enc_emb, encx, bid & 15, bid >> 4); return; }
  if (bid < 256)        { int s = bid - 128;  gather_body(oseq, dec_emb, decx, s & 15, s >> 4); return; }
  if (bid < 768)        { int s = bid - 256;  swz_body(Wx_f, wxf_s, 2048, s >> 3, (s & 7) * 256 + threadIdx.x); return; }
  if (bid < 1280)       { int s = bid - 768;  swz_body(Wx_b, wxb_s, 2048, s >> 3, (s & 7) * 256 + threadIdx.x); return; }
  { int s = bid - 1280; swz_body(Wx_d, wxd_s, 4096, s >> 4, (s & 15) * 256 + threadIdx.x); }
}

// ---- xw GEMMs for both encoder directions in one launch -------------------
__global__ __launch_bounds__(256) void xw_enc_gemm(
    const short* __restrict__ encx, const short* __restrict__ wxf_s,
    const short* __restrict__ wxb_s, float* xw_f, float* xw_b) {
  gemm_body(encx, blockIdx.z ? wxb_s : wxf_s, blockIdx.z ? xw_b : xw_f,
            nullptr, 512, 2048, 512, blockIdx.x, blockIdx.y, false);
}

// ---- encoder LSTM (blocks 0..63) + xw_d GEMM (64..191) + Wo swizzle -------
__global__ __launch_bounds__(256, 1) void lstm_enc_fused(
    const float* __restrict__ Wh_f, const float* __restrict__ Wh_b,
    const float* __restrict__ xw_f, const float* __restrict__ xw_b,
    const float* __restrict__ b_f, const float* __restrict__ b_b,
    unsigned* hb_f, unsigned* hb_b, float* enc_out, float* encT,
    const short* __restrict__ decx, const short* __restrict__ wxd_s,
    float* xw_d, const float* __restrict__ Wo, short* wo_s) {
  const int bid = blockIdx.x;
  const int tid = threadIdx.x;
  if (bid >= 192) {          // Wo swizzle: 16000 blocks, N=32000, 128 k8-rows
    int sb = bid - 192;
    int k8 = sb / 125, nb = sb - k8 * 125;
    swz_body(Wo, wo_s, 32000, k8, nb * 256 + tid);
    return;
  }
  if (bid >= 64) {           // xw_d = decx @ wxd_s : 128 blocks
    int gb = bid - 64;
    gemm_body(decx, wxd_s, xw_d, nullptr, 512, 4096, 512, gb & 31, gb >> 5, false);
    return;
  }
  // ---------------- LSTM role ----------------
  const int dir = bid >> 5;
  const int u0  = (bid & 31) * 16;
  const int w = tid >> 6, lane = tid & 63;
  const int q = lane >> 4, l15 = lane & 15;
  const float* Wh   = dir ? Wh_b : Wh_f;
  const float* xw   = dir ? xw_b : xw_f;
  const float* bias = dir ? b_b : b_f;
  unsigned* hb = dir ? hb_b : hb_f;

  __shared__ short hs[5][520];    // h staged bf16; row 4 = zeros (pad rows)
  __shared__ float zb[4][4][16];  // [gate][b][unit]
  __shared__ float cb[4][16];     // cell state [b][unit]
  if (tid < 64) {
    cb[tid >> 4][tid & 15] = 0.f;
    // publish h0 = 0 with tag 1 (parity 0) EARLY so peers' polls can pass
    st_coh(hb + (tid >> 4) * 512 + u0 + (tid & 15), 1u << 16);
  }
  for (int k = tid; k < 520; k += 256) hs[4][k] = 0;

  const int col = w * 512 + u0 + l15;       // gate column in [0,2048)
  const float bcol = bias[col];
  bf16x8 wfrag[16];                          // Wh fragments, live in VGPRs
#pragma unroll
  for (int ks = 0; ks < 16; ++ks) {
    bf16x8 v;
#pragma unroll
    for (int jj = 0; jj < 8; ++jj) {
      int k = ks * 32 + q * 8 + jj;
      v[jj] = f2bf(Wh[(size_t)k * 2048 + col]);
    }
    wfrag[ks] = v;
  }
  const short* hp = hs[(l15 < 4) ? l15 : 4];
  float xwv[4];
  if (q == 0) {
    int tx0 = dir ? 127 : 0;
#pragma unroll
    for (int r = 0; r < 4; ++r) xwv[r] = xw[((size_t)(r * 128 + tx0)) * 2048 + col];
  }
  __syncthreads();

#pragma unroll 1
  for (int t = 0; t < 128; ++t) {
    // batched poll: reload ALL words in parallel each round
    const unsigned exp_ = (unsigned)(t + 1);
    const unsigned* src = hb + (t & 1) * 2048;
    unsigned v[8];
    bool ok;
    int guard = 0;
    do {
#pragma unroll
      for (int j = 0; j < 8; ++j) v[j] = ld_coh(src + j * 256 + tid);
      ok = true;
#pragma unroll
      for (int j = 0; j < 8; ++j) ok &= ((v[j] >> 16) == exp_);
      if (!ok) __builtin_amdgcn_s_sleep(1);
    } while (!ok && ++guard < (1 << 14));
#pragma unroll
    for (int j = 0; j < 8; ++j) {
      unsigned idx = j * 256 + tid;
      hs[idx >> 9][idx & 511] = (short)(v[j] & 0xffffu);
    }
    __syncthreads();

    f32x4 a0 = (f32x4){0.f, 0.f, 0.f, 0.f}, a1 = a0;
#pragma unroll
    for (int ks = 0; ks < 16; ks += 2) {
      bf16x8 f0 = *(const bf16x8*)(hp + ks * 32 + q * 8);
      bf16x8 f1 = *(const bf16x8*)(hp + (ks + 1) * 32 + q * 8);
      a0 = __builtin_amdgcn_mfma_f32_16x16x32_bf16(f0, wfrag[ks], a0, 0, 0, 0);
      a1 = __builtin_amdgcn_mfma_f32_16x16x32_bf16(f1, wfrag[ks + 1], a1, 0, 0, 0);
    }
    const int tx = dir ? (127 - t) : t;
    if (q == 0) {
#pragma unroll
      for (int r = 0; r < 4; ++r) zb[w][r][l15] = a0[r] + a1[r] + xwv[r] + bcol;
      if (t < 127) {                        // prefetch next step's xw
        int txn = dir ? (126 - t) : (t + 1);
#pragma unroll
        for (int r = 0; r < 4; ++r) xwv[r] = xw[((size_t)(r * 128 + txn)) * 2048 + col];
      }
    }
    __syncthreads();
    if (tid < 64) {
      int b = tid >> 4, u = tid & 15;
      float zi = zb[0][b][u], zf = zb[1][b][u], zg = zb[2][b][u], zo = zb[3][b][u];
      float c = sigf(zf) * cb[b][u] + sigf(zi) * tanhf_fast(zg);
      cb[b][u] = c;
      float h = sigf(zo) * tanhf_fast(c);
      if (t < 127)
        st_coh(hb + ((t + 1) & 1) * 2048 + b * 512 + u0 + u,
               ((unsigned)(t + 2) << 16) | (unsigned short)f2bf(h));
      int d = dir * 512 + u0 + u;
      enc_out[((size_t)(b * 128 + tx)) * 1024 + d] = h;
      encT[((size_t)(b * 1024 + d)) * 128 + tx] = h;
    }
    // no trailing barrier: next staging writes only hs (MFMA reads done before
    // the zb barrier); zb/cb hazards covered by the post-staging barrier.
  }
}

// ---- decoder LSTM: 64 WGs x 256, D=1024 -----------------------------------
__global__ __launch_bounds__(256, 1) void lstm_dec(
    const float* __restrict__ Wh_d, const float* __restrict__ xw_d,
    const float* __restrict__ b_d, const float* __restrict__ enc_out,
    unsigned* hb, float* dec_out) {
  const int u0  = blockIdx.x * 16;
  const int tid = threadIdx.x;
  const int w = tid >> 6, lane = tid & 63;
  const int q = lane >> 4, l15 = lane & 15;

  __shared__ short hs[5][1032];   // row 4 = zeros
  __shared__ float zb[4][4][16];
  __shared__ float cb[4][16];
  if (tid < 64) {
    int b = tid >> 4, u = tid & 15;
    cb[b][u] = 0.f;
    float h0 = enc_out[((size_t)(b * 128 + 127)) * 1024 + u0 + u];
    st_coh(hb + b * 1024 + u0 + u, (1u << 16) | (unsigned short)f2bf(h0));
  }
  for (int k = tid; k < 1032; k += 256) hs[4][k] = 0;

  const int col = w * 1024 + u0 + l15;      // gate column in [0,4096)
  const float bcol = b_d[col];
  bf16x8 wfrag[32];
#pragma unroll
  for (int ks = 0; ks < 32; ++ks) {
    bf16x8 v;
#pragma unroll
    for (int jj = 0; jj < 8; ++jj) {
      int k = ks * 32 + q * 8 + jj;
      v[jj] = f2bf(Wh_d[(size_t)k * 4096 + col]);
    }
    wfrag[ks] = v;
  }
  const short* hp = hs[(l15 < 4) ? l15 : 4];
  float xwv[4];
  if (q == 0) {
#pragma unroll
    for (int r = 0; r < 4; ++r) xwv[r] = xw_d[((size_t)(r * 128)) * 4096 + col];
  }
  __syncthreads();

#pragma unroll 1
  for (int t = 0; t < 128; ++t) {
    const unsigned exp_ = (unsigned)(t + 1);
    const unsigned* src = hb + (t & 1) * 4096;
    unsigned v[16];
    bool ok;
    int guard = 0;
    do {
#pragma unroll
      for (int j = 0; j < 16; ++j) v[j] = ld_coh(src + j * 256 + tid);
      ok = true;
#pragma unroll
      for (int j = 0; j < 16; ++j) ok &= ((v[j] >> 16) == exp_);
      if (!ok) __builtin_amdgcn_s_sleep(1);
    } while (!ok && ++guard < (1 << 14));
#pragma unroll
    for (int j = 0; j < 16; ++j) {
      unsigned idx = j * 256 + tid;
      hs[idx >> 10][idx & 1023] = (short)(v[j] & 0xffffu);
    }
    __syncthreads();

    f32x4 a0 = (f32x4){0.f, 0.f, 0.f, 0.f}, a1 = a0;
#pragma unroll
    for (int ks = 0; ks < 32; ks += 2) {
      bf16x8 f0 = *(const bf16x8*)(hp + ks * 32 + q * 8);
      bf16x8 f1 = *(const bf16x8*)(hp + (ks + 1) * 32 + q * 8);
      a0 = __builtin_amdgcn_mfma_f32_16x16x32_bf16(f0, wfrag[ks], a0, 0, 0, 0);
      a1 = __builtin_amdgcn_mfma_f32_16x16x32_bf16(f1, wfrag[ks + 1], a1, 0, 0, 0);
    }
    if (q == 0) {
#pragma unroll
      for (int r = 0; r < 4; ++r) zb[w][r][l15] = a0[r] + a1[r] + xwv[r] + bcol;
      if (t < 127) {
#pragma unroll
        for (int r = 0; r < 4; ++r) xwv[r] = xw_d[((size_t)(r * 128 + t + 1)) * 4096 + col];
      }
    }
    __syncthreads();
    if (tid < 64) {
      int b = tid >> 4, u = tid & 15;
      float zi = zb[0][b][u], zf = zb[1][b][u], zg = zb[2][b][u], zo = zb[3][b][u];
      float c = sigf(zf) * cb[b][u] + sigf(zi) * tanhf_fast(zg);
      cb[b][u] = c;
      float h = sigf(zo) * tanhf_fast(c);
      if (t < 127)
        st_coh(hb + ((t + 1) & 1) * 4096 + b * 1024 + u0 + u,
               ((unsigned)(t + 2) << 16) | (unsigned short)f2bf(h));
      dec_out[((size_t)(b * 128 + t)) * 1024 + u0 + u] = h;
    }
  }
}

// ---- attention: one block per (b,t); writes swizzled bf16 attn ------------
__global__ __launch_bounds__(256) void attention(
    const float* __restrict__ dec_out, const float* __restrict__ enc_out,
    const float* __restrict__ encT, const float* __restrict__ scale,
    short* __restrict__ attn_swz) {
  const int m = blockIdx.x, b = m >> 7, tid = threadIdx.x;
  __shared__ float dec_s[1024], scl_s[1024];
  __shared__ float red[256], wts[128], sred[2];
  for (int d = tid; d < 1024; d += 256) {
    dec_s[d] = dec_out[(size_t)m * 1024 + d];
    scl_s[d] = scale[d];
  }
  __syncthreads();
  const int s = tid & 127, half = tid >> 7;
  float sc = 0.f;
  const float* ep = encT + (size_t)b * 1024 * 128 + s;
  for (int d = half * 512; d < half * 512 + 512; ++d)
    sc += tanhf_fast(dec_s[d] + ep[(size_t)d * 128]) * scl_s[d];
  red[tid] = sc;
  __syncthreads();
  float v = 0.f;
  if (tid < 128) { v = red[tid] + red[tid + 128]; wts[tid] = v; }
  __syncthreads();
  if (tid < 64) {
    float mx = fmaxf(wts[tid], wts[tid + 64]);
    for (int off = 32; off; off >>= 1) mx = fmaxf(mx, __shfl_down(mx, off));
    if (tid == 0) sred[0] = mx;
  }
  __syncthreads();
  const float MX = sred[0];
  if (tid < 128) { v = __expf(v - MX); wts[tid] = v; }
  __syncthreads();
  if (tid < 64) {
    float sm = wts[tid] + wts[tid + 64];
    for (int off = 32; off; off >>= 1) sm += __shfl_down(sm, off);
    if (tid == 0) sred[1] = sm;
  }
  __syncthreads();
  const float inv = 1.f / sred[1];
  if (tid < 128) wts[tid] = v * inv;
  __syncthreads();
#pragma unroll
  for (int kk = 0; kk < 4; ++kk) {
    int d = tid + kk * 256;
    float a = 0.f;
    for (int ss = 0; ss < 128; ++ss)
      a += wts[ss] * enc_out[((size_t)(b * 128 + ss)) * 1024 + d];
    attn_swz[((size_t)(d >> 3) * 512 + m) * 8 + (d & 7)] = f2bf(a);
  }
}

// ---- logits = attn @ Wo ---------------------------------------------------
__global__ __launch_bounds__(256) void gemm_wo(const short* __restrict__ attn_s,
                                               const short* __restrict__ wo_s,
                                               short* logits) {
  gemm_body(attn_s, wo_s, nullptr, logits, 512, 32000, 1024,
            blockIdx.x, blockIdx.y, true);
}

// ---- row softmax over 32000 vocab, bf16 logits + bias -> fp32 probs -------
__global__ __launch_bounds__(256) void softmax_out(const short* __restrict__ logits,
                                                   const float* __restrict__ bo,
                                                   float* __restrict__ out) {
  const int m = blockIdx.x, tid = threadIdx.x;
  __shared__ float red[256];
  const short* lp = logits + (size_t)m * 32000;
  float mx = -1e30f;
  for (int n = tid; n < 32000; n += 256) mx = fmaxf(mx, b2f(lp[n]) + bo[n]);
  red[tid] = mx;
  __syncthreads();
  for (int s2 = 128; s2 > 0; s2 >>= 1) {
    if (tid < s2) red[tid] = fmaxf(red[tid], red[tid + s2]);
    __syncthreads();
  }
  const float M = red[0];
  __syncthreads();
  float sm = 0.f;
  for (int n = tid; n < 32000; n += 256) sm += __expf(b2f(lp[n]) + bo[n] - M);
  red[tid] = sm;
  __syncthreads();
  for (int s2 = 128; s2 > 0; s2 >>= 1) {
    if (tid < s2) red[tid] += red[tid + s2];
    __syncthreads();
  }
  const float inv = 1.f / red[0];
  for (int n = tid; n < 32000; n += 256)
    out[(size_t)m * 32000 + n] = __expf(b2f(lp[n]) + bo[n] - M) * inv;
}

// ---------------------------------------------------------------------------
extern "C" void kernel_launch(void* const* d_in, const int* in_sizes, int n_in,
                              void* d_out, int out_size, void* d_ws, size_t ws_size,
                              hipStream_t stream) {
  (void)in_sizes; (void)n_in; (void)out_size;
  if (ws_size < WS_NEED) return;

  const int*   input_seq  = (const int*)d_in[0];
  const int*   output_seq = (const int*)d_in[1];
  const float* enc_emb    = (const float*)d_in[2];
  const float* dec_emb    = (const float*)d_in[3];
  const float* Wx_f = (const float*)d_in[4];
  const float* Wh_f = (const float*)d_in[5];
  const float* b_f  = (const float*)d_in[6];
  const float* Wx_b = (const float*)d_in[7];
  const float* Wh_b = (const float*)d_in[8];
  const float* b_b  = (const float*)d_in[9];
  const float* Wx_d = (const float*)d_in[10];
  const float* Wh_d = (const float*)d_in[11];
  const float* b_d  = (const float*)d_in[12];
  const float* attn_scale = (const float*)d_in[13];
  const float* Wo   = (const float*)d_in[14];
  const float* bo   = (const float*)d_in[15];
  float* out = (float*)d_out;

  char* ws = (char*)d_ws;
  unsigned* hbf   = (unsigned*)(ws + OFF_HBF);
  unsigned* hbb   = (unsigned*)(ws + OFF_HBB);
  unsigned* hbd   = (unsigned*)(ws + OFF_HBD);
  short* encx     = (short*)(ws + OFF_ENCX);
  short* decx     = (short*)(ws + OFF_DECX);
  short* wxf_s    = (short*)(ws + OFF_WXF);
  short* wxb_s    = (short*)(ws + OFF_WXB);
  short* wxd_s    = (short*)(ws + OFF_WXD);
  short* wo_s     = (short*)(ws + OFF_WOS);
  float* xw_f     = (float*)(ws + OFF_XWF);
  float* xw_b     = (float*)(ws + OFF_XWB);
  float* xw_d     = (float*)(ws + OFF_XWD);
  float* enc_out  = (float*)(ws + OFF_ENCO);
  float* encT     = (float*)(ws + OFF_ENCT);
  float* dec_out  = (float*)(ws + OFF_DECO);
  short* attn_s   = (short*)(ws + OFF_ATTN);
  short* logits   = (short*)(ws + OFF_LOG);

  // No memset: 0xAA poison yields tag 0xAAAA which never matches a valid tag.

  prep<<<2304, 256, 0, stream>>>(input_seq, output_seq, enc_emb, dec_emb,
                                 Wx_f, Wx_b, Wx_d, encx, decx, wxf_s, wxb_s, wxd_s);
  xw_enc_gemm<<<dim3(16, 4, 2), 256, 0, stream>>>(encx, wxf_s, wxb_s, xw_f, xw_b);
  lstm_enc_fused<<<64 + 128 + 16000, 256, 0, stream>>>(
      Wh_f, Wh_b, xw_f, xw_b, b_f, b_b, hbf, hbb, enc_out, encT,
      decx, wxd_s, xw_d, Wo, wo_s);
  lstm_dec<<<64, 256, 0, stream>>>(Wh_d, xw_d, b_d, enc_out, hbd, dec_out);
  attention<<<512, 256, 0, stream>>>(dec_out, enc_out, encT, attn_scale, attn_s);
  gemm_wo<<<dim3(250, 4), 256, 0, stream>>>(attn_s, wo_s, logits);
  softmax_out<<<512, 256, 0, stream>>>(logits, bo, out);
}